// Round 1
// 810.838 us; speedup vs baseline: 1.4142x; 1.4142x over previous
//
#include <hip/hip_runtime.h>
#include <math.h>

#define SEQ 2048
#define HDIM 2048
#define NHQ 16
#define NHKV 4
#define DH 128
#define NE 16
#define NI 768
#define EPSV 1e-6f
#define QKVS 3072           // row stride of fused qkv fp32 buffer
#define MOE_TILES 48        // max 128-row tiles across experts: 32 + 15 < 48

typedef __attribute__((ext_vector_type(8))) __bf16 bf16x8;
typedef __attribute__((ext_vector_type(4))) float f32x4;
typedef unsigned short ushort_t;

__device__ __forceinline__ ushort_t f2bf(float f) {
    union { float f; unsigned int u; } v; v.f = f;
    unsigned int u = v.u;
    unsigned int r = (u + 0x7FFFu + ((u >> 16) & 1u)) >> 16;
    return (ushort_t)r;
}
__device__ __forceinline__ float bf2f(ushort_t b) {
    union { unsigned int u; float f; } v; v.u = ((unsigned int)b) << 16;
    return v.f;
}
__device__ __forceinline__ void async16(const ushort_t* g, ushort_t* l) {
    __builtin_amdgcn_global_load_lds(
        (const __attribute__((address_space(1))) void*)g,
        (__attribute__((address_space(3))) void*)l, 16, 0, 0);
}

// ---------------- fp32 -> (hi,lo) bf16 split, elementwise (for hidden) ----------------
__global__ void split_cvt(const float* __restrict__ in, ushort_t* __restrict__ hi,
                          ushort_t* __restrict__ lo) {
    int i = blockIdx.x * 256 + threadIdx.x;
    float4 v = ((const float4*)in)[i];
    ushort_t h0 = f2bf(v.x), h1 = f2bf(v.y), h2 = f2bf(v.z), h3 = f2bf(v.w);
    ushort4 h = make_ushort4(h0, h1, h2, h3);
    ushort4 l = make_ushort4(f2bf(v.x - bf2f(h0)), f2bf(v.y - bf2f(h1)),
                             f2bf(v.z - bf2f(h2)), f2bf(v.w - bf2f(h3)));
    ((ushort4*)hi)[i] = h;
    ((ushort4*)lo)[i] = l;
}

// ---------------- transpose K×N fp32 -> N×K (hi,lo) bf16 ----------------
__global__ void transpose_split(const float* __restrict__ in, ushort_t* __restrict__ hi,
                                ushort_t* __restrict__ lo, int K, int N) {
    __shared__ float tls[32][33];
    int tx = threadIdx.x & 31, ty = threadIdx.x >> 5;
    size_t k0 = (size_t)blockIdx.y * 32, n0 = (size_t)blockIdx.x * 32;
    #pragma unroll
    for (int i = 0; i < 32; i += 8) tls[ty + i][tx] = in[(k0 + ty + i) * N + n0 + tx];
    __syncthreads();
    #pragma unroll
    for (int i = 0; i < 32; i += 8) {
        float v = tls[tx][ty + i];
        ushort_t h = f2bf(v);
        size_t o = (n0 + ty + i) * K + k0 + tx;
        hi[o] = h;
        lo[o] = f2bf(v - bf2f(h));
    }
}

// ---------------- transpose K×N fp32 -> N×K bf16, batched over z ----------------
__global__ void transpose_cvt(const float* __restrict__ in, ushort_t* __restrict__ out,
                              int K, int N) {
    const float* ib = in + (size_t)blockIdx.z * K * N;
    ushort_t* ob = out + (size_t)blockIdx.z * K * N;
    __shared__ float tls[32][33];
    int tx = threadIdx.x & 31, ty = threadIdx.x >> 5;
    size_t k0 = (size_t)blockIdx.y * 32, n0 = (size_t)blockIdx.x * 32;
    #pragma unroll
    for (int i = 0; i < 32; i += 8) tls[ty + i][tx] = ib[(k0 + ty + i) * N + n0 + tx];
    __syncthreads();
    #pragma unroll
    for (int i = 0; i < 32; i += 8)
        ob[(n0 + ty + i) * K + k0 + tx] = f2bf(tls[tx][ty + i]);
}

// ---------------- transpose V (from fused qkv fp32) -> [kvh][d][s] split bf16 ----------------
__global__ void vT_split(const float* __restrict__ qkv, ushort_t* __restrict__ vth,
                         ushort_t* __restrict__ vtl) {
    __shared__ float tls[32][33];
    int tx = threadIdx.x & 31, ty = threadIdx.x >> 5;
    int kvh = blockIdx.z;
    size_t s0 = (size_t)blockIdx.x * 32;   // seq tile
    size_t d0 = (size_t)blockIdx.y * 32;   // head-dim tile
    #pragma unroll
    for (int i = 0; i < 32; i += 8)
        tls[ty + i][tx] = qkv[(s0 + ty + i) * QKVS + 2560 + (size_t)kvh * DH + d0 + tx];
    __syncthreads();
    #pragma unroll
    for (int i = 0; i < 32; i += 8) {
        float v = tls[tx][ty + i];
        ushort_t hh = f2bf(v);
        size_t o = ((size_t)kvh * DH + d0 + ty + i) * SEQ + s0 + tx;
        vth[o] = hh;
        vtl[o] = f2bf(v - bf2f(hh));
    }
}

// ---------------- split-bf16 MFMA GEMM: C = A(M×K) @ Bt^T (+R), ~fp32 precision ----------------
// A as (hi,lo) row-major M×K; Bt as (hi,lo) row-major N×K. 128×128 tile, BK=32, 4 waves.
#define BM 128
#define BN 128
#define BK 32
__global__ __launch_bounds__(256, 2)
void gemm_split(const ushort_t* __restrict__ Ahi, const ushort_t* __restrict__ Alo,
                const ushort_t* __restrict__ Bhi, const ushort_t* __restrict__ Blo,
                float* __restrict__ C, int ldc,
                const float* __restrict__ R, ushort_t* __restrict__ Cbf,
                int N, int K) {
    __shared__ ushort_t sAh[BM * BK], sAl[BM * BK], sBh[BN * BK], sBl[BN * BK];
    const int tid = threadIdx.x;
    const int wave = tid >> 6, lane = tid & 63;
    const int wy = wave >> 1, wx = wave & 1;
    const int quad = lane >> 4, m16 = lane & 15;
    const size_t rowBase = (size_t)blockIdx.y * BM;
    const size_t colBase = (size_t)blockIdx.x * BN;
    const int srow = wave * 32 + (lane >> 2);
    const int scol = (lane & 3) * 8;
    const size_t aoff0 = (rowBase + srow) * K + scol;
    const size_t aoff1 = aoff0 + (size_t)16 * K;
    const size_t boff0 = (colBase + srow) * K + scol;
    const size_t boff1 = boff0 + (size_t)16 * K;
    ushort_t* dA0 = &sAh[(wave * 32) * BK];
    ushort_t* dA1 = &sAh[(wave * 32 + 16) * BK];
    ushort_t* dAl0 = &sAl[(wave * 32) * BK];
    ushort_t* dAl1 = &sAl[(wave * 32 + 16) * BK];
    ushort_t* dB0 = &sBh[(wave * 32) * BK];
    ushort_t* dB1 = &sBh[(wave * 32 + 16) * BK];
    ushort_t* dBl0 = &sBl[(wave * 32) * BK];
    ushort_t* dBl1 = &sBl[(wave * 32 + 16) * BK];
    f32x4 acc[4][4] = {};
    for (int k0 = 0; k0 < K; k0 += BK) {
        __syncthreads();
        async16(Ahi + aoff0 + k0, dA0);
        async16(Ahi + aoff1 + k0, dA1);
        async16(Alo + aoff0 + k0, dAl0);
        async16(Alo + aoff1 + k0, dAl1);
        async16(Bhi + boff0 + k0, dB0);
        async16(Bhi + boff1 + k0, dB1);
        async16(Blo + boff0 + k0, dBl0);
        async16(Blo + boff1 + k0, dBl1);
        __syncthreads();
        bf16x8 ah[4], al[4], bh[4], bl[4];
        #pragma unroll
        for (int i = 0; i < 4; i++) {
            ah[i] = *(const bf16x8*)&sAh[(wy * 64 + i * 16 + m16) * BK + quad * 8];
            al[i] = *(const bf16x8*)&sAl[(wy * 64 + i * 16 + m16) * BK + quad * 8];
        }
        #pragma unroll
        for (int j = 0; j < 4; j++) {
            bh[j] = *(const bf16x8*)&sBh[(wx * 64 + j * 16 + m16) * BK + quad * 8];
            bl[j] = *(const bf16x8*)&sBl[(wx * 64 + j * 16 + m16) * BK + quad * 8];
        }
        #pragma unroll
        for (int i = 0; i < 4; i++)
            #pragma unroll
            for (int j = 0; j < 4; j++) {
                acc[i][j] = __builtin_amdgcn_mfma_f32_16x16x32_bf16(ah[i], bh[j], acc[i][j], 0, 0, 0);
                acc[i][j] = __builtin_amdgcn_mfma_f32_16x16x32_bf16(ah[i], bl[j], acc[i][j], 0, 0, 0);
                acc[i][j] = __builtin_amdgcn_mfma_f32_16x16x32_bf16(al[i], bh[j], acc[i][j], 0, 0, 0);
            }
    }
    #pragma unroll
    for (int i = 0; i < 4; i++)
        #pragma unroll
        for (int j = 0; j < 4; j++)
            #pragma unroll
            for (int r = 0; r < 4; r++) {
                size_t row = rowBase + wy * 64 + i * 16 + quad * 4 + r;
                size_t col = colBase + wx * 64 + j * 16 + m16;
                float v = acc[i][j][r];
                if (R) v += R[row * N + col];
                C[row * ldc + col] = v;
                if (Cbf) Cbf[row * N + col] = f2bf(v);
            }
}

// ---------------- per-(seq,head) RMSNorm + RoPE; emits split-bf16 Q/K ----------------
// Q out: [h][s][d] hi/lo ; K out: [kvh][s][d] hi/lo
__global__ void norm_rope(const float* __restrict__ qkv, const float* __restrict__ q_scale,
                          const float* __restrict__ k_scale,
                          ushort_t* __restrict__ qh, ushort_t* __restrict__ ql,
                          ushort_t* __restrict__ kh, ushort_t* __restrict__ kl) {
    const int s = blockIdx.x;
    const int h = blockIdx.y;
    const int t = threadIdx.x;
    const float* ptr;
    const float* scale;
    if (h < NHQ) { ptr = qkv + (size_t)s * QKVS + h * DH; scale = q_scale; }
    else         { ptr = qkv + (size_t)s * QKVS + 2048 + (h - NHQ) * DH; scale = k_scale; }
    __shared__ float sh[DH];
    __shared__ float red[128];
    float x = ptr[t];
    red[t] = x * x;
    __syncthreads();
    #pragma unroll
    for (int off = 64; off > 0; off >>= 1) {
        if (t < off) red[t] += red[t + off];
        __syncthreads();
    }
    float var = red[0] * (1.0f / DH);
    float r = rsqrtf(var + EPSV);
    float xn = x * r * scale[t];
    sh[t] = xn;
    __syncthreads();
    int i = t & 63;
    float inv_freq = exp2f(-(float)i * 0.20762050593046014f);
    float ang = (float)s * inv_freq;
    float c = cosf(ang), sn = sinf(ang);
    float y;
    if (t < 64) y = xn * c - sh[t + 64] * sn;
    else        y = xn * c + sh[t - 64] * sn;
    ushort_t yh = f2bf(y);
    ushort_t yl = f2bf(y - bf2f(yh));
    if (h < NHQ) {
        size_t o = ((size_t)h * SEQ + s) * DH + t;
        qh[o] = yh; ql[o] = yl;
    } else {
        size_t o = ((size_t)(h - NHQ) * SEQ + s) * DH + t;
        kh[o] = yh; kl[o] = yl;
    }
}

// ---------------- MFMA flash attention, split-bf16 3-term (~fp32 precision) ----------------
// 64 Q-rows per block (16 per wave), K-tile 64. Q/K split in [h][s][d]; V^T split in [kvh][d][s].
#define AQT 64
#define AKT 64
__global__ __launch_bounds__(256, 2)
void attn_flash(const ushort_t* __restrict__ qh_b, const ushort_t* __restrict__ ql_b,
                const ushort_t* __restrict__ kh_b, const ushort_t* __restrict__ kl_b,
                const ushort_t* __restrict__ vth_b, const ushort_t* __restrict__ vtl_b,
                ushort_t* __restrict__ ohi, ushort_t* __restrict__ olo) {
    const int by = blockIdx.y;                  // head
    const int bx = blockIdx.x;
    const int qb = (by < 8) ? bx : (31 - bx);   // load balance across CUs
    const int h = by;
    const int kvh = h >> 2;
    const int r0 = qb * AQT;
    const int tid = threadIdx.x;
    const int wave = tid >> 6, lane = tid & 63;
    const int quad = lane >> 4, m16 = lane & 15;

    // XOR-chunk-swizzled tiles: 16B chunk c of row n stored at slot (c ^ (n&7)).
    __shared__ ushort_t sKh[AKT * DH], sKl[AKT * DH];       // [64][128] 16KB each
    __shared__ ushort_t sVh[DH * AKT], sVl[DH * AKT];       // [128][64] 16KB each
    __shared__ ushort_t sPh[4 * 16 * AKT], sPl[4 * 16 * AKT]; // per-wave [16][64] 8KB each

    // Q fragments resident in registers (hi/lo), rows wave*16 + m16
    bf16x8 qfh[4], qfl[4];
    {
        const size_t qrow = ((size_t)h * SEQ + r0 + wave * 16 + m16) * DH;
        #pragma unroll
        for (int kk = 0; kk < 4; kk++) {
            qfh[kk] = *(const bf16x8*)&qh_b[qrow + kk * 32 + quad * 8];
            qfl[kk] = *(const bf16x8*)&ql_b[qrow + kk * 32 + quad * 8];
        }
    }

    f32x4 accO[8] = {};
    float mrow[4], lrow[4];
    #pragma unroll
    for (int r = 0; r < 4; r++) { mrow[r] = -3.0e38f; lrow[r] = 0.f; }

    const float scl = 0.08838834764831845f;
    const int nkt = qb + 1;

    for (int kt = 0; kt < nkt; kt++) {
        __syncthreads();
        // stage K tile [64][128] hi/lo, global source pre-swizzled so LDS lands swizzled
        #pragma unroll
        for (int i = 0; i < 4; i++) {
            int seg = i * 4 + wave;                 // 16 × 1KB segments
            int row = seg * 4 + (lane >> 4);        // 0..63
            int clog = (lane & 15) ^ (row & 7);
            size_t gk = ((size_t)kvh * SEQ + kt * AKT + row) * DH + clog * 8;
            async16(kh_b + gk, &sKh[seg * 512]);
            async16(kl_b + gk, &sKl[seg * 512]);
        }
        // stage V^T tile [128][64] hi/lo
        #pragma unroll
        for (int i = 0; i < 4; i++) {
            int seg = i * 4 + wave;
            int row = seg * 8 + (lane >> 3);        // 0..127 (d)
            int clog = (lane & 7) ^ (row & 7);
            size_t gv = ((size_t)kvh * DH + row) * SEQ + kt * AKT + clog * 8;
            async16(vth_b + gv, &sVh[seg * 512]);
            async16(vtl_b + gv, &sVl[seg * 512]);
        }
        __syncthreads();

        // QK^T: S(16×64 per wave) = Q · K^T, 3-term split
        f32x4 accS[4] = {};
        #pragma unroll
        for (int kk = 0; kk < 4; kk++) {
            #pragma unroll
            for (int j = 0; j < 4; j++) {
                int n = j * 16 + m16;
                int c = (kk * 4 + quad) ^ (n & 7);
                bf16x8 bh = *(const bf16x8*)&sKh[n * 128 + c * 8];
                bf16x8 bl = *(const bf16x8*)&sKl[n * 128 + c * 8];
                accS[j] = __builtin_amdgcn_mfma_f32_16x16x32_bf16(qfh[kk], bh, accS[j], 0, 0, 0);
                accS[j] = __builtin_amdgcn_mfma_f32_16x16x32_bf16(qfl[kk], bh, accS[j], 0, 0, 0);
                accS[j] = __builtin_amdgcn_mfma_f32_16x16x32_bf16(qfh[kk], bl, accS[j], 0, 0, 0);
            }
        }

        // mask + scale + online softmax (row = quad*4+r within wave's 16 rows)
        const int diag = (kt == qb);
        float tmax[4];
        #pragma unroll
        for (int r = 0; r < 4; r++) tmax[r] = -3.0e38f;
        #pragma unroll
        for (int j = 0; j < 4; j++)
            #pragma unroll
            for (int r = 0; r < 4; r++) {
                float s = accS[j][r] * scl;
                if (diag) {
                    int ra = wave * 16 + quad * 4 + r;
                    int ca = j * 16 + m16;
                    if (ca > ra) s = -3.0e38f;
                }
                accS[j][r] = s;
                tmax[r] = fmaxf(tmax[r], s);
            }
        #pragma unroll
        for (int r = 0; r < 4; r++) {
            #pragma unroll
            for (int w = 1; w < 16; w <<= 1)
                tmax[r] = fmaxf(tmax[r], __shfl_xor(tmax[r], w));
            float newm = fmaxf(mrow[r], tmax[r]);
            float alpha = __expf(mrow[r] - newm);
            mrow[r] = newm;
            float psum = 0.f;
            #pragma unroll
            for (int j = 0; j < 4; j++) {
                float p = __expf(accS[j][r] - newm);
                accS[j][r] = p;
                psum += p;
            }
            #pragma unroll
            for (int w = 1; w < 16; w <<= 1) psum += __shfl_xor(psum, w);
            lrow[r] = lrow[r] * alpha + psum;
            #pragma unroll
            for (int j2 = 0; j2 < 8; j2++) accO[j2][r] *= alpha;
        }

        // P -> per-wave LDS (hi/lo), swizzled to match A-frag reads
        #pragma unroll
        for (int j = 0; j < 4; j++)
            #pragma unroll
            for (int r = 0; r < 4; r++) {
                int pr = quad * 4 + r;
                int cb = j * 32 + m16 * 2;                       // byte col
                int sw = (cb ^ ((pr & 7) << 4)) >> 1;            // ushort col
                float p = accS[j][r];
                ushort_t ph = f2bf(p);
                sPh[wave * 1024 + pr * 64 + sw] = ph;
                sPl[wave * 1024 + pr * 64 + sw] = f2bf(p - bf2f(ph));
            }
        __syncthreads();

        // PV: O(16×128 per wave) += P · V^T, 3-term split
        #pragma unroll
        for (int kk2 = 0; kk2 < 2; kk2++) {
            int cpa = (kk2 * 4 + quad) ^ (m16 & 7);
            bf16x8 pah = *(const bf16x8*)&sPh[wave * 1024 + m16 * 64 + cpa * 8];
            bf16x8 pal = *(const bf16x8*)&sPl[wave * 1024 + m16 * 64 + cpa * 8];
            #pragma unroll
            for (int j2 = 0; j2 < 8; j2++) {
                int n = j2 * 16 + m16;
                int c = (kk2 * 4 + quad) ^ (n & 7);
                bf16x8 vh = *(const bf16x8*)&sVh[n * 64 + c * 8];
                bf16x8 vl = *(const bf16x8*)&sVl[n * 64 + c * 8];
                accO[j2] = __builtin_amdgcn_mfma_f32_16x16x32_bf16(pah, vh, accO[j2], 0, 0, 0);
                accO[j2] = __builtin_amdgcn_mfma_f32_16x16x32_bf16(pal, vh, accO[j2], 0, 0, 0);
                accO[j2] = __builtin_amdgcn_mfma_f32_16x16x32_bf16(pah, vl, accO[j2], 0, 0, 0);
            }
        }
    }

    // epilogue: normalize, write split attn output [s][h*128+d]
    #pragma unroll
    for (int r = 0; r < 4; r++) {
        float inv = 1.0f / lrow[r];
        size_t ra = (size_t)r0 + wave * 16 + quad * 4 + r;
        #pragma unroll
        for (int j2 = 0; j2 < 8; j2++) {
            float val = accO[j2][r] * inv;
            size_t o = ra * (NHQ * DH) + (size_t)h * DH + j2 * 16 + m16;
            ushort_t hh = f2bf(val);
            ohi[o] = hh;
            olo[o] = f2bf(val - bf2f(hh));
        }
    }
}

// ---------------- router logits + top-2 + expert grouping ----------------
__global__ void router_topk(const float* __restrict__ hbuf, const float* __restrict__ rw,
                            float* __restrict__ logits_out, int* __restrict__ cnt,
                            int* __restrict__ plist) {
    const int tok = blockIdx.x;
    const int tid = threadIdx.x;
    __shared__ float part[256];
    const int e = tid & 15, chunk = tid >> 4;
    const float* hr = hbuf + (size_t)tok * HDIM;
    float sum = 0.f;
    const int k0 = chunk * 128;
    for (int x = k0; x < k0 + 128; x++) sum += hr[x] * rw[(size_t)x * NE + e];
    part[tid] = sum;
    __syncthreads();
    if (tid < 16) {
        float s = 0.f;
        #pragma unroll
        for (int c = 0; c < 16; c++) s += part[c * 16 + tid];
        part[tid] = s;
    }
    __syncthreads();
    if (tid == 0) {
        float best = -1e30f; int bi = 0;
        for (int e2 = 0; e2 < 16; e2++) if (part[e2] > best) { best = part[e2]; bi = e2; }
        float best2 = -1e30f; int bi2 = 0;
        for (int e2 = 0; e2 < 16; e2++) if (e2 != bi && part[e2] > best2) { best2 = part[e2]; bi2 = e2; }
        int p0 = atomicAdd(&cnt[bi], 1);
        plist[bi * SEQ + p0] = tok * 2;
        int p1 = atomicAdd(&cnt[bi2], 1);
        plist[bi2 * SEQ + p1] = tok * 2 + 1;
    }
    if (tid < 16) logits_out[(size_t)tok * NE + tid] = part[tid];
}

// ---------------- tile map (128-row tiles) ----------------
__global__ void tilemap(const int* __restrict__ cnt, int* __restrict__ te,
                        int* __restrict__ to, int* __restrict__ ntiles) {
    if (threadIdx.x == 0 && blockIdx.x == 0) {
        int n = 0;
        for (int e = 0; e < NE; e++) {
            int c = cnt[e];
            for (int off = 0; off < c; off += BM) { te[n] = e; to[n] = off; n++; }
        }
        *ntiles = n;
    }
}

// ---------------- MoE up: gather-A bf16 MFMA GEMM, silu epilogue -> U bf16 ----------------
__global__ __launch_bounds__(256, 2)
void moe_up_mfma(const ushort_t* __restrict__ hbf, const int* __restrict__ plist,
                 const int* __restrict__ cnt, const int* __restrict__ te,
                 const int* __restrict__ to, const int* __restrict__ nt,
                 const ushort_t* __restrict__ wupt, const float* __restrict__ b_up,
                 ushort_t* __restrict__ U) {
    const int t = blockIdx.y;
    if (t >= *nt) return;
    const int ex = te[t], r0 = to[t], cnt_e = cnt[ex];
    __shared__ int sp[BM];
    __shared__ ushort_t sA[BM * BK], sB[BN * BK];
    const int tid = threadIdx.x;
    if (tid < BM) {
        int idx = r0 + tid;
        sp[tid] = (idx < cnt_e) ? plist[ex * SEQ + idx] : 0;
    }
    __syncthreads();
    const int wave = tid >> 6, lane = tid & 63;
    const int wy = wave >> 1, wx = wave & 1;
    const int quad = lane >> 4, m16 = lane & 15;
    const int srow = wave * 32 + (lane >> 2);
    const int scol = (lane & 3) * 8;
    const int p0 = sp[srow], p1 = sp[srow + 16];
    const ushort_t* Ag0 = hbf + (size_t)(p0 >> 1) * HDIM + scol;
    const ushort_t* Ag1 = hbf + (size_t)(p1 >> 1) * HDIM + scol;
    const size_t colBase = (size_t)blockIdx.x * BN;
    const ushort_t* Bt = wupt + (size_t)ex * HDIM * NI;
    const ushort_t* Bg0 = Bt + (colBase + srow) * HDIM + scol;
    const ushort_t* Bg1 = Bg0 + (size_t)16 * HDIM;
    ushort_t* dA0 = &sA[(wave * 32) * BK];
    ushort_t* dA1 = &sA[(wave * 32 + 16) * BK];
    ushort_t* dB0 = &sB[(wave * 32) * BK];
    ushort_t* dB1 = &sB[(wave * 32 + 16) * BK];
    f32x4 acc[4][4] = {};
    for (int k0 = 0; k0 < HDIM; k0 += BK) {
        __syncthreads();
        async16(Ag0 + k0, dA0);
        async16(Ag1 + k0, dA1);
        async16(Bg0 + k0, dB0);
        async16(Bg1 + k0, dB1);
        __syncthreads();
        bf16x8 af[4], bfr[4];
        #pragma unroll
        for (int i = 0; i < 4; i++)
            af[i] = *(const bf16x8*)&sA[(wy * 64 + i * 16 + m16) * BK + quad * 8];
        #pragma unroll
        for (int j = 0; j < 4; j++)
            bfr[j] = *(const bf16x8*)&sB[(wx * 64 + j * 16 + m16) * BK + quad * 8];
        #pragma unroll
        for (int i = 0; i < 4; i++)
            #pragma unroll
            for (int j = 0; j < 4; j++)
                acc[i][j] = __builtin_amdgcn_mfma_f32_16x16x32_bf16(af[i], bfr[j], acc[i][j], 0, 0, 0);
    }
    #pragma unroll
    for (int i = 0; i < 4; i++)
        #pragma unroll
        for (int j = 0; j < 4; j++)
            #pragma unroll
            for (int r = 0; r < 4; r++) {
                int rl = wy * 64 + i * 16 + quad * 4 + r;
                if (r0 + rl < cnt_e) {
                    int p = sp[rl];
                    size_t col = colBase + wx * 64 + j * 16 + m16;
                    float x = acc[i][j][r] + b_up[(size_t)ex * NI + col];
                    U[(size_t)p * NI + col] = f2bf(x / (1.0f + __expf(-x)));
                }
            }
}

// ---------------- MoE down: gather-A bf16 MFMA GEMM, atomicAdd into h ----------------
__global__ __launch_bounds__(256, 2)
void moe_down_mfma(const ushort_t* __restrict__ U, const int* __restrict__ plist,
                   const int* __restrict__ cnt, const int* __restrict__ te,
                   const int* __restrict__ to, const int* __restrict__ nt,
                   const ushort_t* __restrict__ wdnt, const float* __restrict__ b_down,
                   float* __restrict__ hout) {
    const int t = blockIdx.y;
    if (t >= *nt) return;
    const int ex = te[t], r0 = to[t], cnt_e = cnt[ex];
    __shared__ int sp[BM];
    __shared__ ushort_t sA[BM * BK], sB[BN * BK];
    const int tid = threadIdx.x;
    if (tid < BM) {
        int idx = r0 + tid;
        sp[tid] = (idx < cnt_e) ? plist[ex * SEQ + idx] : 0;
    }
    __syncthreads();
    const int wave = tid >> 6, lane = tid & 63;
    const int wy = wave >> 1, wx = wave & 1;
    const int quad = lane >> 4, m16 = lane & 15;
    const int srow = wave * 32 + (lane >> 2);
    const int scol = (lane & 3) * 8;
    const int p0 = sp[srow], p1 = sp[srow + 16];
    const ushort_t* Ag0 = U + (size_t)p0 * NI + scol;
    const ushort_t* Ag1 = U + (size_t)p1 * NI + scol;
    const size_t colBase = (size_t)blockIdx.x * BN;
    const ushort_t* Bt = wdnt + (size_t)ex * NI * HDIM;
    const ushort_t* Bg0 = Bt + (colBase + srow) * NI + scol;
    const ushort_t* Bg1 = Bg0 + (size_t)16 * NI;
    ushort_t* dA0 = &sA[(wave * 32) * BK];
    ushort_t* dA1 = &sA[(wave * 32 + 16) * BK];
    ushort_t* dB0 = &sB[(wave * 32) * BK];
    ushort_t* dB1 = &sB[(wave * 32 + 16) * BK];
    f32x4 acc[4][4] = {};
    for (int k0 = 0; k0 < NI; k0 += BK) {
        __syncthreads();
        async16(Ag0 + k0, dA0);
        async16(Ag1 + k0, dA1);
        async16(Bg0 + k0, dB0);
        async16(Bg1 + k0, dB1);
        __syncthreads();
        bf16x8 af[4], bfr[4];
        #pragma unroll
        for (int i = 0; i < 4; i++)
            af[i] = *(const bf16x8*)&sA[(wy * 64 + i * 16 + m16) * BK + quad * 8];
        #pragma unroll
        for (int j = 0; j < 4; j++)
            bfr[j] = *(const bf16x8*)&sB[(wx * 64 + j * 16 + m16) * BK + quad * 8];
        #pragma unroll
        for (int i = 0; i < 4; i++)
            #pragma unroll
            for (int j = 0; j < 4; j++)
                acc[i][j] = __builtin_amdgcn_mfma_f32_16x16x32_bf16(af[i], bfr[j], acc[i][j], 0, 0, 0);
    }
    #pragma unroll
    for (int i = 0; i < 4; i++)
        #pragma unroll
        for (int j = 0; j < 4; j++)
            #pragma unroll
            for (int r = 0; r < 4; r++) {
                int rl = wy * 64 + i * 16 + quad * 4 + r;
                if (r0 + rl < cnt_e) {
                    int tok = sp[rl] >> 1;
                    size_t col = colBase + wx * 64 + j * 16 + m16;
                    float v = acc[i][j][r] + b_down[(size_t)ex * HDIM + col];
                    atomicAdd(&hout[(size_t)tok * HDIM + col], v);
                }
            }
}

extern "C" void kernel_launch(void* const* d_in, const int* in_sizes, int n_in,
                              void* d_out, int out_size, void* d_ws, size_t ws_size,
                              hipStream_t stream) {
    (void)in_sizes; (void)n_in; (void)out_size; (void)ws_size;
    const float* hidden   = (const float*)d_in[0];
    const float* wq       = (const float*)d_in[1];
    const float* wk       = (const float*)d_in[2];
    const float* wv       = (const float*)d_in[3];
    const float* wo       = (const float*)d_in[4];
    const float* q_scale  = (const float*)d_in[5];
    const float* k_scale  = (const float*)d_in[6];
    const float* router_w = (const float*)d_in[7];
    const float* w_up     = (const float*)d_in[8];
    const float* b_up     = (const float*)d_in[9];
    const float* w_down   = (const float*)d_in[10];
    const float* b_down   = (const float*)d_in[11];

    float* out = (float*)d_out;
    float* h_out      = out;
    float* logits_out = out + (size_t)SEQ * HDIM;

    // ---- workspace layout (ushort units) ----
    // phase-1 pool (dead after out-proj):
    //   hid_hi/lo (2×4.19M), wqkv_hi/lo (2×6.29M), qkv fp32 (6.29M f = 12.58M us),
    //   attn_hi/lo (2×4.19M), wo_hi/lo (2×4.19M)     = 50.33M us
    // attention split buffers overlay hid_*/wqkv_* (dead after QKV GEMM):
    //   q split (2×4.19M) over hid_hi/lo; k split (2×1.05M) + vT split (2×1.05M) over wqkv_hi
    // phase-2 pool (overlays phase-1):
    //   w_up_t (25.17M), w_down_t (25.17M), U (3.15M) = 53.48M us
    ushort_t* pool = (ushort_t*)d_ws;
    ushort_t* hid_hi  = pool;
    ushort_t* hid_lo  = hid_hi + (size_t)4194304;
    ushort_t* wqkv_hi = hid_lo + (size_t)4194304;
    ushort_t* wqkv_lo = wqkv_hi + (size_t)6291456;
    float*    qkv     = (float*)(wqkv_lo + (size_t)6291456);
    ushort_t* attn_hi = (ushort_t*)(qkv + (size_t)6291456);
    ushort_t* attn_lo = attn_hi + (size_t)4194304;
    ushort_t* wo_hi   = attn_lo + (size_t)4194304;
    ushort_t* wo_lo   = wo_hi + (size_t)4194304;

    // attention split buffers (valid after QKV GEMM, dead after attn)
    ushort_t* qsp_h = hid_hi;
    ushort_t* qsp_l = hid_lo;
    ushort_t* ksp_h = wqkv_hi;
    ushort_t* ksp_l = wqkv_hi + (size_t)1048576;
    ushort_t* vt_h  = wqkv_hi + (size_t)2097152;
    ushort_t* vt_l  = wqkv_hi + (size_t)3145728;

    ushort_t* w_up_t  = pool;                               // phase 2 overlay
    ushort_t* w_dn_t  = w_up_t + (size_t)25165824;
    ushort_t* U_ws    = w_dn_t + (size_t)25165824;          // ends at 53.48M us

    ushort_t* hbf     = pool + (size_t)53477376;            // after max(pool phases)
    int* cnt_ws   = (int*)(hbf + (size_t)4194304);
    int* plist_ws = cnt_ws + 16;
    int* te_ws    = plist_ws + NE * SEQ;
    int* to_ws    = te_ws + 64;
    int* nt_ws    = to_ws + 64;

    // 1. split hidden -> bf16 hi/lo
    split_cvt<<<dim3(4096), 256, 0, stream>>>(hidden, hid_hi, hid_lo);
    // 2. transpose+split weights for pre-router GEMMs
    transpose_split<<<dim3(64, 64), 256, 0, stream>>>(wq, wqkv_hi, wqkv_lo, HDIM, 2048);
    transpose_split<<<dim3(16, 64), 256, 0, stream>>>(wk, wqkv_hi + (size_t)2048 * HDIM,
                                                      wqkv_lo + (size_t)2048 * HDIM, HDIM, 512);
    transpose_split<<<dim3(16, 64), 256, 0, stream>>>(wv, wqkv_hi + (size_t)2560 * HDIM,
                                                      wqkv_lo + (size_t)2560 * HDIM, HDIM, 512);
    transpose_split<<<dim3(64, 64), 256, 0, stream>>>(wo, wo_hi, wo_lo, HDIM, HDIM);

    // 3. fused QKV projection (split-bf16 MFMA, ~fp32 precision)
    gemm_split<<<dim3(QKVS / BN, SEQ / BM), 256, 0, stream>>>(
        hid_hi, hid_lo, wqkv_hi, wqkv_lo, qkv, QKVS, nullptr, nullptr, QKVS, HDIM);

    // 4. RMSNorm + RoPE -> split-bf16 Q/K; transpose V -> split-bf16 V^T
    //    (these overwrite hid_*/wqkv_*, which are dead after step 3)
    norm_rope<<<dim3(SEQ, NHQ + NHKV), 128, 0, stream>>>(qkv, q_scale, k_scale,
                                                         qsp_h, qsp_l, ksp_h, ksp_l);
    vT_split<<<dim3(64, 4, 4), 256, 0, stream>>>(qkv, vt_h, vt_l);

    // 5. MFMA flash attention (split-bf16 3-term) -> split-bf16 attn output
    attn_flash<<<dim3(SEQ / AQT, NHQ), 256, 0, stream>>>(
        qsp_h, qsp_l, ksp_h, ksp_l, vt_h, vt_l, attn_hi, attn_lo);

    // 6. out-proj + residual -> h fp32 (d_out) + bf16 mirror hbf
    gemm_split<<<dim3(HDIM / BN, SEQ / BM), 256, 0, stream>>>(
        attn_hi, attn_lo, wo_hi, wo_lo, h_out, HDIM, hidden, hbf, HDIM, HDIM);

    // 7. MoE weight transposes (after out-proj: they overlay phase-1 buffers)
    transpose_cvt<<<dim3(24, 64, 16), 256, 0, stream>>>(w_up, w_up_t, HDIM, NI);
    transpose_cvt<<<dim3(64, 24, 16), 256, 0, stream>>>(w_down, w_dn_t, NI, HDIM);

    // 8. router + grouping
    hipMemsetAsync(cnt_ws, 0, NE * sizeof(int), stream);
    router_topk<<<dim3(SEQ), 256, 0, stream>>>(h_out, router_w, logits_out, cnt_ws, plist_ws);
    tilemap<<<1, 64, 0, stream>>>(cnt_ws, te_ws, to_ws, nt_ws);

    // 9. expert-grouped MoE (bf16 MFMA), down-proj atomically accumulates into h
    moe_up_mfma<<<dim3(NI / BN, MOE_TILES), 256, 0, stream>>>(
        hbf, plist_ws, cnt_ws, te_ws, to_ws, nt_ws, w_up_t, b_up, U_ws);
    moe_down_mfma<<<dim3(HDIM / BN, MOE_TILES), 256, 0, stream>>>(
        U_ws, plist_ws, cnt_ws, te_ws, to_ws, nt_ws, w_dn_t, b_down, h_out);
}